// Round 2
// baseline (788.228 us; speedup 1.0000x reference)
//
#include <hip/hip_runtime.h>
#include <hip/hip_bf16.h>

// ---------------------------------------------------------------------------
// Swin cross-attention block, MI355X (gfx950).
// Config: B=16, H=W=56, C=512, WS=7, SHIFT=3, NH=16, HD=32, N=49, NW=64.
// M = B*NW*N = 50176 rows. Only q_b, k_a, v_a are consumed by the reference.
//
// Workspace layout (~260 MB):
//   xw   : 50176x512 bf16 (LN'd+shifted+windowed rescaled)  [reused: attn_out]
//   yw   : 50176x512 bf16 (rescaler stream)
//   qb/kb/vb : (1024,16,49,32) bf16 each
//   Wt   : 2048x512 bf16  rows 0-511   = Wqkv_b[:, 0:512]^T    (q weights)
//                         rows 512-1535 = Wqkv_a[:, 512:1536]^T (k,v weights)
//                         rows 1536-2047 = Wproj^T
// ---------------------------------------------------------------------------

typedef short bf16x8 __attribute__((ext_vector_type(8)));
typedef float f32x4 __attribute__((ext_vector_type(4)));
typedef unsigned short u16;

#define MTOT 50176             // 1024 windows * 49
#define SCALE_ 0.17677669529663687f

__device__ __forceinline__ u16 f2bf(float f) {
    __hip_bfloat16 h = __float2bfloat16(f);
    return *reinterpret_cast<u16*>(&h);
}
__device__ __forceinline__ float bf2f(u16 u) {
    union { unsigned int i; float f; } t; t.i = ((unsigned int)u) << 16; return t.f;
}

#define ASYNC_COPY16(g, l)                                                      \
    __builtin_amdgcn_global_load_lds((__attribute__((address_space(1))) void*)(g), \
                                     (__attribute__((address_space(3))) void*)(l), 16, 0, 0)

// ---------------------------------------------------------------------------
// Kernel 1: weight transpose + fp32->bf16 convert.  Wt[r][k], r = output col.
// ---------------------------------------------------------------------------
__global__ __launch_bounds__(256) void wconv_kernel(
    const float* __restrict__ Wqkv_a, const float* __restrict__ Wqkv_b,
    const float* __restrict__ Wproj, u16* __restrict__ Wt)
{
    const int idx = blockIdx.x * 256 + threadIdx.x;   // 2048*512
    const int r = idx >> 9;
    const int k = idx & 511;
    float val;
    if (r < 512)       val = Wqkv_b[k * 1536 + r];
    else if (r < 1536) val = Wqkv_a[k * 1536 + r];
    else               val = Wproj[k * 512 + (r - 1536)];
    Wt[idx] = f2bf(val);
}

// ---------------------------------------------------------------------------
// Kernel 2: LayerNorm + roll(-3,-3) + window partition, both streams -> bf16.
// One wave per destination row; 8 floats per lane.
// ---------------------------------------------------------------------------
__device__ __forceinline__ void ln_one(
    const float* __restrict__ src, const float* __restrict__ g,
    const float* __restrict__ bt, u16* __restrict__ dst, int lane)
{
    const float4 v0 = *(const float4*)(src + lane * 8);
    const float4 v1 = *(const float4*)(src + lane * 8 + 4);
    float s = v0.x + v0.y + v0.z + v0.w + v1.x + v1.y + v1.z + v1.w;
    float q = v0.x*v0.x + v0.y*v0.y + v0.z*v0.z + v0.w*v0.w
            + v1.x*v1.x + v1.y*v1.y + v1.z*v1.z + v1.w*v1.w;
#pragma unroll
    for (int o = 32; o >= 1; o >>= 1) { s += __shfl_xor(s, o); q += __shfl_xor(q, o); }
    const float mean = s * (1.0f / 512.0f);
    const float rstd = rsqrtf(q * (1.0f / 512.0f) - mean * mean + 1e-5f);
    const float4 g0 = *(const float4*)(g + lane * 8);
    const float4 g1 = *(const float4*)(g + lane * 8 + 4);
    const float4 b0 = *(const float4*)(bt + lane * 8);
    const float4 b1 = *(const float4*)(bt + lane * 8 + 4);
    u16 o8[8];
    o8[0] = f2bf((v0.x - mean) * rstd * g0.x + b0.x);
    o8[1] = f2bf((v0.y - mean) * rstd * g0.y + b0.y);
    o8[2] = f2bf((v0.z - mean) * rstd * g0.z + b0.z);
    o8[3] = f2bf((v0.w - mean) * rstd * g0.w + b0.w);
    o8[4] = f2bf((v1.x - mean) * rstd * g1.x + b1.x);
    o8[5] = f2bf((v1.y - mean) * rstd * g1.y + b1.y);
    o8[6] = f2bf((v1.z - mean) * rstd * g1.z + b1.z);
    o8[7] = f2bf((v1.w - mean) * rstd * g1.w + b1.w);
    int4 pk;
    pk.x = (int)(((unsigned)o8[1] << 16) | o8[0]);
    pk.y = (int)(((unsigned)o8[3] << 16) | o8[2]);
    pk.z = (int)(((unsigned)o8[5] << 16) | o8[4]);
    pk.w = (int)(((unsigned)o8[7] << 16) | o8[6]);
    *(int4*)(dst + lane * 8) = pk;
}

__global__ __launch_bounds__(256) void ln_window_kernel(
    const float* __restrict__ xa, const float* __restrict__ xb,
    const float* __restrict__ ga, const float* __restrict__ bea,
    const float* __restrict__ gb, const float* __restrict__ beb,
    u16* __restrict__ xw, u16* __restrict__ yw)
{
    const int wave = threadIdx.x >> 6, lane = threadIdx.x & 63;
    const int row = blockIdx.x * 4 + wave;             // < 50176
    const int win = row / 49, n = row - win * 49;
    const int b = win >> 6, wi = win & 63;
    const int wh = wi >> 3, ww = wi & 7;
    const int ih = n / 7, iw = n - ih * 7;
    int h = wh * 7 + ih + 3; if (h >= 56) h -= 56;     // roll(-3): src = dst+3
    int w = ww * 7 + iw + 3; if (w >= 56) w -= 56;
    const size_t src = ((size_t)b * 3136 + (size_t)h * 56 + w) * 512;
    const size_t dst = (size_t)row * 512;
    ln_one(xa + src, ga, bea, xw + dst, lane);
    ln_one(xb + src, gb, beb, yw + dst, lane);
}

// ---------------------------------------------------------------------------
// GEMM mainloop (m97 structure): 128x128 tile, BK=64, 4 waves, 16x16x32 bf16,
// global_load_lds width 16.  A: (M,512) bf16 row-major.  B: Wt rows (N,512).
// ---------------------------------------------------------------------------
#define GEMM_PROLOG()                                                           \
    __shared__ __align__(16) u16 As[128 * 64];                                  \
    __shared__ __align__(16) u16 Bs[128 * 64];                                  \
    const int tid = threadIdx.x;                                                \
    const int lane = tid & 63;                                                  \
    const int wv = tid >> 6;                                                    \
    const int wr = wv >> 1, wc = wv & 1;                                        \
    const int rowl = lane & 15, kg = lane >> 4;                                 \
    f32x4 acc[4][4];                                                            \
    for (int i = 0; i < 4; ++i)                                                 \
        for (int j = 0; j < 4; ++j)                                             \
            acc[i][j] = (f32x4){0.f, 0.f, 0.f, 0.f};                            \
    const int sr = tid >> 3;                                                    \
    const int scc = (tid & 7) * 8;                                              \
    const u16* Ab = Asrc + (size_t)(mt * 128 + sr) * 512 + scc;                 \
    const u16* Bb = Bsrc + (size_t)sr * 512 + scc;                              \
    char* AsDst = (char*)As + tid * 16;                                         \
    char* BsDst = (char*)Bs + tid * 16;                                         \
    for (int kt = 0; kt < 8; ++kt) {                                            \
        const int k0 = kt * 64;                                                 \
        _Pragma("unroll")                                                       \
        for (int i = 0; i < 4; ++i) {                                           \
            ASYNC_COPY16(Ab + (size_t)i * 32 * 512 + k0, AsDst + i * 4096);     \
            ASYNC_COPY16(Bb + (size_t)i * 32 * 512 + k0, BsDst + i * 4096);     \
        }                                                                       \
        asm volatile("s_waitcnt vmcnt(0)" ::: "memory");                        \
        __syncthreads();                                                        \
        _Pragma("unroll")                                                       \
        for (int kk = 0; kk < 64; kk += 32) {                                   \
            bf16x8 af[4], bfr[4];                                               \
            _Pragma("unroll")                                                   \
            for (int i = 0; i < 4; ++i)                                         \
                af[i] = *(const bf16x8*)(As + (wr * 64 + i * 16 + rowl) * 64 + kk + kg * 8); \
            _Pragma("unroll")                                                   \
            for (int j = 0; j < 4; ++j)                                         \
                bfr[j] = *(const bf16x8*)(Bs + (wc * 64 + j * 16 + rowl) * 64 + kk + kg * 8); \
            _Pragma("unroll")                                                   \
            for (int i = 0; i < 4; ++i) {                                       \
                _Pragma("unroll")                                               \
                for (int j = 0; j < 4; ++j)                                     \
                    acc[i][j] = __builtin_amdgcn_mfma_f32_16x16x32_bf16(        \
                        af[i], bfr[j], acc[i][j], 0, 0, 0);                     \
            }                                                                   \
        }                                                                       \
        __syncthreads();                                                        \
    }

// Kernel 3: q/k/v projection.  1-D grid 4704 = 392 mt x 12 nt, nt-fastest
// (12 consecutive blocks share one A panel) + bijective XCD swizzle.
// nt 0-3: q (A=yw, Wqkv_b cols); nt 4-11: k,v (A=xw, Wqkv_a cols).
__global__ __launch_bounds__(256) void gemm_qkv_kernel(
    const u16* __restrict__ xw, const u16* __restrict__ yw,
    const u16* __restrict__ Wt,
    const float* __restrict__ bqkv_a, const float* __restrict__ bqkv_b,
    u16* __restrict__ qb, u16* __restrict__ kb, u16* __restrict__ vb)
{
    const int bid = blockIdx.x;                       // 4704 = 8 * 588
    const int swz = (bid & 7) * 588 + (bid >> 3);     // XCD-contiguous chunks
    const int nt = swz % 12;
    const int mt = swz / 12;
    const u16* Asrc = (nt < 4) ? yw : xw;
    const u16* Bsrc = Wt + (size_t)(nt * 128) * 512;
    GEMM_PROLOG()

#pragma unroll
    for (int j = 0; j < 4; ++j) {
        const int col = nt * 128 + wc * 64 + j * 16 + rowl;   // 0..1535
        const bool isq = (col < 512);
        const float bias = isq ? bqkv_b[col] : bqkv_a[col];
        u16* dst = isq ? qb : (col < 1024 ? kb : vb);
        const int head = (col & 511) >> 5;
        const int d = col & 31;
#pragma unroll
        for (int i = 0; i < 4; ++i) {
#pragma unroll
            for (int r = 0; r < 4; ++r) {
                const int row = mt * 128 + wr * 64 + i * 16 + kg * 4 + r;
                const int win = row / 49;
                const int nw = row - win * 49;
                float val = acc[i][j][r] + bias;
                if (isq) val *= SCALE_;
                dst[((size_t)(win * 16 + head) * 49 + nw) * 32 + d] = f2bf(val);
            }
        }
    }
}

// Kernel 5: output projection + bias + window_reverse + roll(+3,+3), fp32 out.
// 1-D grid 1568 = 392 mt x 4 nt, nt-fastest + XCD swizzle.
__global__ __launch_bounds__(256) void gemm_proj_kernel(
    const u16* __restrict__ attn_out, const u16* __restrict__ WtProj,
    const float* __restrict__ bproj, float* __restrict__ out)
{
    const int bid = blockIdx.x;                       // 1568 = 8 * 196
    const int swz = (bid & 7) * 196 + (bid >> 3);
    const int nt = swz & 3;
    const int mt = swz >> 2;
    const u16* Asrc = attn_out;
    const u16* Bsrc = WtProj + (size_t)(nt * 128) * 512;
    GEMM_PROLOG()

#pragma unroll
    for (int j = 0; j < 4; ++j) {
        const int col = nt * 128 + wc * 64 + j * 16 + rowl;   // 0..511
        const float bias = bproj[col];
#pragma unroll
        for (int i = 0; i < 4; ++i) {
#pragma unroll
            for (int r = 0; r < 4; ++r) {
                const int row = mt * 128 + wr * 64 + i * 16 + kg * 4 + r;
                const int win = row / 49;
                const int nw = row - win * 49;
                const int b = win >> 6, wi = win & 63;
                const int wh = wi >> 3, ww = wi & 7;
                const int ih = nw / 7, iw = nw - ih * 7;
                int h = wh * 7 + ih + 3; if (h >= 56) h -= 56;  // roll(+3)
                int w = ww * 7 + iw + 3; if (w >= 56) w -= 56;
                out[((size_t)b * 3136 + (size_t)h * 56 + w) * 512 + col] =
                    acc[i][j][r] + bias;
            }
        }
    }
}

// ---------------------------------------------------------------------------
// Kernel 4: windowed cross-attention, one block per (window, head).
// LDS layout: q/k/v as [49][32] fp32 with float4 slot XOR-swizzle
//   addr(row, d) = row*32 + ((d>>2 ^ (row&7))<<2) + (d&3)
// so lane-strided row reads of any fixed float4 slot spread across banks.
// Softmax: 4-wave shuffle-reduce (all 64 lanes active per row).
// ---------------------------------------------------------------------------
__device__ __forceinline__ int region_(int x) { return (x < 49) ? 0 : ((x < 53) ? 1 : 2); }

__global__ __launch_bounds__(256) void attn_kernel(
    const u16* __restrict__ qb, const u16* __restrict__ kb,
    const u16* __restrict__ vb, const float* __restrict__ rpb,
    u16* __restrict__ attn_out)
{
    __shared__ float qs[49 * 32], ks[49 * 32], vs[49 * 32];
    __shared__ float sc[49 * 52];
    const int tid = threadIdx.x;
    const int wh_id = blockIdx.x;                 // win*16 + head
    const int win = wh_id >> 4, head = wh_id & 15;
    const size_t base = (size_t)wh_id * 1568;     // 49*32 elements

    // --- load q,k,v: 196 threads x 8 bf16 each, swizzled float4 LDS stores
    if (tid < 196) {
        const int t8 = tid * 8;
        const int i = t8 >> 5, d = t8 & 31;       // d in {0,8,16,24}
        const int sa = ((d >> 2) ^ (i & 7)) << 2;
        const int sb = (((d >> 2) + 1) ^ (i & 7)) << 2;
        const bf16x8 rq = *(const bf16x8*)(qb + base + t8);
        const bf16x8 rk = *(const bf16x8*)(kb + base + t8);
        const bf16x8 rv = *(const bf16x8*)(vb + base + t8);
        float4 lo, hi;
        lo.x = bf2f((u16)rq[0]); lo.y = bf2f((u16)rq[1]); lo.z = bf2f((u16)rq[2]); lo.w = bf2f((u16)rq[3]);
        hi.x = bf2f((u16)rq[4]); hi.y = bf2f((u16)rq[5]); hi.z = bf2f((u16)rq[6]); hi.w = bf2f((u16)rq[7]);
        *(float4*)(qs + i * 32 + sa) = lo;
        *(float4*)(qs + i * 32 + sb) = hi;
        lo.x = bf2f((u16)rk[0]); lo.y = bf2f((u16)rk[1]); lo.z = bf2f((u16)rk[2]); lo.w = bf2f((u16)rk[3]);
        hi.x = bf2f((u16)rk[4]); hi.y = bf2f((u16)rk[5]); hi.z = bf2f((u16)rk[6]); hi.w = bf2f((u16)rk[7]);
        *(float4*)(ks + i * 32 + sa) = lo;
        *(float4*)(ks + i * 32 + sb) = hi;
        lo.x = bf2f((u16)rv[0]); lo.y = bf2f((u16)rv[1]); lo.z = bf2f((u16)rv[2]); lo.w = bf2f((u16)rv[3]);
        hi.x = bf2f((u16)rv[4]); hi.y = bf2f((u16)rv[5]); hi.z = bf2f((u16)rv[6]); hi.w = bf2f((u16)rv[7]);
        *(float4*)(vs + i * 32 + sa) = lo;
        *(float4*)(vs + i * 32 + sb) = hi;
    }
    __syncthreads();

    // --- scores + rpb + shifted-window mask
    const int wi = win & 63;
    const int wh = wi >> 3, ww = wi & 7;
    for (int s = tid; s < 2401; s += 256) {
        const int i = s / 49, j = s - i * 49;
        float a = 0.0f;
#pragma unroll
        for (int d4 = 0; d4 < 8; ++d4) {
            const float4 qv = *(const float4*)(qs + i * 32 + ((d4 ^ (i & 7)) << 2));
            const float4 kv = *(const float4*)(ks + j * 32 + ((d4 ^ (j & 7)) << 2));
            a += qv.x * kv.x + qv.y * kv.y + qv.z * kv.z + qv.w * kv.w;
        }
        const int ih = i / 7, iw = i - (i / 7) * 7;
        const int jh = j / 7, jw = j - (j / 7) * 7;
        a += rpb[((ih - jh + 6) * 13 + (iw - jw + 6)) * 16 + head];
        const int li = region_(wh * 7 + ih) * 3 + region_(ww * 7 + iw);
        const int lj = region_(wh * 7 + jh) * 3 + region_(ww * 7 + jw);
        if (li != lj) a -= 100.0f;
        sc[i * 52 + j] = a;
    }
    __syncthreads();

    // --- softmax: wave w handles rows w, w+4, ... ; full-wave shuffle reduce
    {
        const int wvv = tid >> 6, ln = tid & 63;
        for (int r = wvv; r < 49; r += 4) {
            const float v = (ln < 49) ? sc[r * 52 + ln] : -3.0e38f;
            float m = v;
#pragma unroll
            for (int o = 32; o >= 1; o >>= 1) m = fmaxf(m, __shfl_xor(m, o));
            const float e = (ln < 49) ? __expf(v - m) : 0.0f;
            float sm = e;
#pragma unroll
            for (int o = 32; o >= 1; o >>= 1) sm += __shfl_xor(sm, o);
            if (ln < 49) sc[r * 52 + ln] = e * __frcp_rn(sm);
        }
    }
    __syncthreads();

    // --- PV: thread t -> (row i, float4 slot d4); 392 items over 256 threads
    for (int t = tid; t < 392; t += 256) {
        const int i = t >> 3, d4 = t & 7;
        float4 acc; acc.x = acc.y = acc.z = acc.w = 0.0f;
        for (int j = 0; j < 49; ++j) {
            const float sb = sc[i * 52 + j];
            const float4 vv = *(const float4*)(vs + j * 32 + ((d4 ^ (j & 7)) << 2));
            acc.x += sb * vv.x; acc.y += sb * vv.y; acc.z += sb * vv.z; acc.w += sb * vv.w;
        }
        short4 st;
        st.x = (short)f2bf(acc.x); st.y = (short)f2bf(acc.y);
        st.z = (short)f2bf(acc.z); st.w = (short)f2bf(acc.w);
        *(short4*)(attn_out + (size_t)(win * 49 + i) * 512 + head * 32 + d4 * 4) = st;
    }
}

// ---------------------------------------------------------------------------
extern "C" void kernel_launch(void* const* d_in, const int* in_sizes, int n_in,
                              void* d_out, int out_size, void* d_ws, size_t ws_size,
                              hipStream_t stream) {
    (void)in_sizes; (void)n_in; (void)out_size; (void)ws_size;
    const float* rescaled = (const float*)d_in[0];
    const float* rescaler = (const float*)d_in[1];
    const float* gamma_a  = (const float*)d_in[2];
    const float* beta_a   = (const float*)d_in[3];
    const float* gamma_b  = (const float*)d_in[4];
    const float* beta_b   = (const float*)d_in[5];
    const float* Wqkv_a   = (const float*)d_in[6];
    const float* bqkv_a   = (const float*)d_in[7];
    const float* Wqkv_b   = (const float*)d_in[8];
    const float* bqkv_b   = (const float*)d_in[9];
    const float* rpb      = (const float*)d_in[10];
    const float* Wproj    = (const float*)d_in[11];
    const float* bproj    = (const float*)d_in[12];
    float* out = (float*)d_out;

    char* ws = (char*)d_ws;
    const size_t SZ = (size_t)MTOT * 512 * 2;     // 51,380,224 B per bf16 plane
    u16* xw = (u16*)ws;                           // reused as attn_out
    u16* yw = (u16*)(ws + SZ);
    u16* qb = (u16*)(ws + 2 * SZ);
    u16* kb = (u16*)(ws + 3 * SZ);
    u16* vb = (u16*)(ws + 4 * SZ);
    u16* Wt = (u16*)(ws + 5 * SZ);                // 2 MB
    u16* attn_out = xw;

    wconv_kernel<<<4096, 256, 0, stream>>>(Wqkv_a, Wqkv_b, Wproj, Wt);
    ln_window_kernel<<<MTOT / 4, 256, 0, stream>>>(
        rescaled, rescaler, gamma_a, beta_a, gamma_b, beta_b, xw, yw);
    gemm_qkv_kernel<<<4704, 256, 0, stream>>>(
        xw, yw, Wt, bqkv_a, bqkv_b, qb, kb, vb);
    attn_kernel<<<16384, 256, 0, stream>>>(qb, kb, vb, rpb, attn_out);
    gemm_proj_kernel<<<1568, 256, 0, stream>>>(
        attn_out, Wt + (size_t)1536 * 512, bproj, out);
}

// Round 3
// 578.070 us; speedup vs baseline: 1.3636x; 1.3636x over previous
//
#include <hip/hip_runtime.h>
#include <hip/hip_bf16.h>

// ---------------------------------------------------------------------------
// Swin cross-attention block, MI355X (gfx950).
// Config: B=16, H=W=56, C=512, WS=7, SHIFT=3, NH=16, HD=32, N=49, NW=64.
// M = B*NW*N = 50176 rows. Only q_b, k_a, v_a are consumed by the reference.
//
// Workspace (~260 MB):
//   xw : 50176x512 bf16  [reused as attn_out]
//   yw : 50176x512 bf16
//   qb/kb/vb : 50176x512 bf16 (row=win*49+n, col=head*32+d)
//   Wt : 2048x512 bf16 (transposed weight panels)
//   bias : [4 masks][16 heads][64][64] fp32 (rpb + window mask + pad mask)
// ---------------------------------------------------------------------------

typedef short bf16x8 __attribute__((ext_vector_type(8)));
typedef float f32x4 __attribute__((ext_vector_type(4)));
typedef unsigned short u16;

#define MTOT 50176
#define SCALE_ 0.17677669529663687f

__device__ __forceinline__ u16 f2bf(float f) {
    __hip_bfloat16 h = __float2bfloat16(f);
    return *reinterpret_cast<u16*>(&h);
}
__device__ __forceinline__ float bf2f(u16 u) {
    union { unsigned int i; float f; } t; t.i = ((unsigned int)u) << 16; return t.f;
}

#define ASYNC_COPY16(g, l)                                                      \
    __builtin_amdgcn_global_load_lds((__attribute__((address_space(1))) void*)(g), \
                                     (__attribute__((address_space(3))) void*)(l), 16, 0, 0)

// ---------------------------------------------------------------------------
// Kernel 1: weight transpose + fp32->bf16.  Wt[r][k], r = output col.
// ---------------------------------------------------------------------------
__global__ __launch_bounds__(256) void wconv_kernel(
    const float* __restrict__ Wqkv_a, const float* __restrict__ Wqkv_b,
    const float* __restrict__ Wproj, u16* __restrict__ Wt)
{
    const int idx = blockIdx.x * 256 + threadIdx.x;   // 2048*512
    const int r = idx >> 9;
    const int k = idx & 511;
    float val;
    if (r < 512)       val = Wqkv_b[k * 1536 + r];
    else if (r < 1536) val = Wqkv_a[k * 1536 + r];
    else               val = Wproj[k * 512 + (r - 1536)];
    Wt[idx] = f2bf(val);
}

// ---------------------------------------------------------------------------
// Kernel 1b: per-(mask,head) bias table: rpb + shifted-window mask, padded
// cols/rows (>=49) = -3e38.  bias[(mid*16+head)*4096 + i*64 + j].
// mid = (wh==7)*2 + (ww==7).
// ---------------------------------------------------------------------------
__global__ __launch_bounds__(256) void build_bias_kernel(
    const float* __restrict__ rpb, float* __restrict__ bias)
{
    const int blk = blockIdx.x;           // 64 = mid*16 + head
    const int mid = blk >> 4, head = blk & 15;
    const int whq = (mid >> 1) & 1, wwq = mid & 1;
    for (int t = threadIdx.x; t < 4096; t += 256) {
        const int i = t >> 6, j = t & 63;
        float v;
        if (i < 49 && j < 49) {
            const int ih = i / 7, iw = i - ih * 7;
            const int jh = j / 7, jw = j - jh * 7;
            v = rpb[((ih - jh + 6) * 13 + (iw - jw + 6)) * 16 + head];
            const int li = (whq ? (ih < 4 ? 1 : 2) : 0) * 3 + (wwq ? (iw < 4 ? 1 : 2) : 0);
            const int lj = (whq ? (jh < 4 ? 1 : 2) : 0) * 3 + (wwq ? (jw < 4 ? 1 : 2) : 0);
            if (li != lj) v -= 100.0f;
        } else {
            v = -3.0e38f;
        }
        bias[(size_t)blk * 4096 + t] = v;
    }
}

// ---------------------------------------------------------------------------
// Kernel 2: LayerNorm + roll(-3,-3) + window partition, both streams -> bf16.
// ---------------------------------------------------------------------------
__device__ __forceinline__ void ln_one(
    const float* __restrict__ src, const float* __restrict__ g,
    const float* __restrict__ bt, u16* __restrict__ dst, int lane)
{
    const float4 v0 = *(const float4*)(src + lane * 8);
    const float4 v1 = *(const float4*)(src + lane * 8 + 4);
    float s = v0.x + v0.y + v0.z + v0.w + v1.x + v1.y + v1.z + v1.w;
    float q = v0.x*v0.x + v0.y*v0.y + v0.z*v0.z + v0.w*v0.w
            + v1.x*v1.x + v1.y*v1.y + v1.z*v1.z + v1.w*v1.w;
#pragma unroll
    for (int o = 32; o >= 1; o >>= 1) { s += __shfl_xor(s, o); q += __shfl_xor(q, o); }
    const float mean = s * (1.0f / 512.0f);
    const float rstd = rsqrtf(q * (1.0f / 512.0f) - mean * mean + 1e-5f);
    const float4 g0 = *(const float4*)(g + lane * 8);
    const float4 g1 = *(const float4*)(g + lane * 8 + 4);
    const float4 b0 = *(const float4*)(bt + lane * 8);
    const float4 b1 = *(const float4*)(bt + lane * 8 + 4);
    u16 o8[8];
    o8[0] = f2bf((v0.x - mean) * rstd * g0.x + b0.x);
    o8[1] = f2bf((v0.y - mean) * rstd * g0.y + b0.y);
    o8[2] = f2bf((v0.z - mean) * rstd * g0.z + b0.z);
    o8[3] = f2bf((v0.w - mean) * rstd * g0.w + b0.w);
    o8[4] = f2bf((v1.x - mean) * rstd * g1.x + b1.x);
    o8[5] = f2bf((v1.y - mean) * rstd * g1.y + b1.y);
    o8[6] = f2bf((v1.z - mean) * rstd * g1.z + b1.z);
    o8[7] = f2bf((v1.w - mean) * rstd * g1.w + b1.w);
    int4 pk;
    pk.x = (int)(((unsigned)o8[1] << 16) | o8[0]);
    pk.y = (int)(((unsigned)o8[3] << 16) | o8[2]);
    pk.z = (int)(((unsigned)o8[5] << 16) | o8[4]);
    pk.w = (int)(((unsigned)o8[7] << 16) | o8[6]);
    *(int4*)(dst + lane * 8) = pk;
}

__global__ __launch_bounds__(256) void ln_window_kernel(
    const float* __restrict__ xa, const float* __restrict__ xb,
    const float* __restrict__ ga, const float* __restrict__ bea,
    const float* __restrict__ gb, const float* __restrict__ beb,
    u16* __restrict__ xw, u16* __restrict__ yw)
{
    const int wave = threadIdx.x >> 6, lane = threadIdx.x & 63;
    const int row = blockIdx.x * 4 + wave;             // < 50176
    const int win = row / 49, n = row - win * 49;
    const int b = win >> 6, wi = win & 63;
    const int wh = wi >> 3, ww = wi & 7;
    const int ih = n / 7, iw = n - ih * 7;
    int h = wh * 7 + ih + 3; if (h >= 56) h -= 56;     // roll(-3)
    int w = ww * 7 + iw + 3; if (w >= 56) w -= 56;
    const size_t src = ((size_t)b * 3136 + (size_t)h * 56 + w) * 512;
    const size_t dst = (size_t)row * 512;
    ln_one(xa + src, ga, bea, xw + dst, lane);
    ln_one(xb + src, gb, beb, yw + dst, lane);
}

// ---------------------------------------------------------------------------
// GEMM mainloop (m97 structure): 128x128 tile, BK=64, 4 waves, 16x16x32 bf16.
// ---------------------------------------------------------------------------
#define GEMM_PROLOG()                                                           \
    __shared__ __align__(16) u16 As[128 * 64];                                  \
    __shared__ __align__(16) u16 Bs[128 * 64];                                  \
    const int tid = threadIdx.x;                                                \
    const int lane = tid & 63;                                                  \
    const int wv = tid >> 6;                                                    \
    const int wr = wv >> 1, wc = wv & 1;                                        \
    const int rowl = lane & 15, kg = lane >> 4;                                 \
    f32x4 acc[4][4];                                                            \
    for (int i = 0; i < 4; ++i)                                                 \
        for (int j = 0; j < 4; ++j)                                             \
            acc[i][j] = (f32x4){0.f, 0.f, 0.f, 0.f};                            \
    const int sr = tid >> 3;                                                    \
    const int scc = (tid & 7) * 8;                                              \
    const u16* Ab = Asrc + (size_t)(mt * 128 + sr) * 512 + scc;                 \
    const u16* Bb = Bsrc + (size_t)sr * 512 + scc;                              \
    char* AsDst = (char*)As + tid * 16;                                         \
    char* BsDst = (char*)Bs + tid * 16;                                         \
    for (int kt = 0; kt < 8; ++kt) {                                            \
        const int k0 = kt * 64;                                                 \
        _Pragma("unroll")                                                       \
        for (int i = 0; i < 4; ++i) {                                           \
            ASYNC_COPY16(Ab + (size_t)i * 32 * 512 + k0, AsDst + i * 4096);     \
            ASYNC_COPY16(Bb + (size_t)i * 32 * 512 + k0, BsDst + i * 4096);     \
        }                                                                       \
        asm volatile("s_waitcnt vmcnt(0)" ::: "memory");                        \
        __syncthreads();                                                        \
        _Pragma("unroll")                                                       \
        for (int kk = 0; kk < 64; kk += 32) {                                   \
            bf16x8 af[4], bfr[4];                                               \
            _Pragma("unroll")                                                   \
            for (int i = 0; i < 4; ++i)                                         \
                af[i] = *(const bf16x8*)(As + (wr * 64 + i * 16 + rowl) * 64 + kk + kg * 8); \
            _Pragma("unroll")                                                   \
            for (int j = 0; j < 4; ++j)                                         \
                bfr[j] = *(const bf16x8*)(Bs + (wc * 64 + j * 16 + rowl) * 64 + kk + kg * 8); \
            _Pragma("unroll")                                                   \
            for (int i = 0; i < 4; ++i) {                                       \
                _Pragma("unroll")                                               \
                for (int j = 0; j < 4; ++j)                                     \
                    acc[i][j] = __builtin_amdgcn_mfma_f32_16x16x32_bf16(        \
                        af[i], bfr[j], acc[i][j], 0, 0, 0);                     \
            }                                                                   \
        }                                                                       \
        __syncthreads();                                                        \
    }

// Kernel 3: q/k/v projection.  Contiguous C-write into (50176,512) planes.
// nt 0-3: q (A=yw); 4-7: k (A=xw); 8-11: v (A=xw).
__global__ __launch_bounds__(256) void gemm_qkv_kernel(
    const u16* __restrict__ xw, const u16* __restrict__ yw,
    const u16* __restrict__ Wt,
    const float* __restrict__ bqkv_a, const float* __restrict__ bqkv_b,
    u16* __restrict__ qb, u16* __restrict__ kb, u16* __restrict__ vb)
{
    const int bid = blockIdx.x;                       // 4704 = 8 * 588
    const int swz = (bid & 7) * 588 + (bid >> 3);     // XCD-contiguous chunks
    const int nt = swz % 12;
    const int mt = swz / 12;
    const u16* Asrc = (nt < 4) ? yw : xw;
    const u16* Bsrc = Wt + (size_t)(nt * 128) * 512;
    GEMM_PROLOG()

#pragma unroll
    for (int j = 0; j < 4; ++j) {
        const int col = nt * 128 + wc * 64 + j * 16 + rowl;   // 0..1535
        const bool isq = (col < 512);
        const float bias_ = isq ? bqkv_b[col] : bqkv_a[col];
        u16* dst = isq ? qb : (col < 1024 ? kb : vb);
        const int pcol = col & 511;
#pragma unroll
        for (int i = 0; i < 4; ++i) {
#pragma unroll
            for (int r = 0; r < 4; ++r) {
                const int row = mt * 128 + wr * 64 + i * 16 + kg * 4 + r;
                float val = acc[i][j][r] + bias_;
                if (isq) val *= SCALE_;
                dst[(size_t)row * 512 + pcol] = f2bf(val);
            }
        }
    }
}

// Kernel 5: output projection + bias + window_reverse + roll(+3,+3), fp32 out.
__global__ __launch_bounds__(256) void gemm_proj_kernel(
    const u16* __restrict__ attn_out, const u16* __restrict__ WtProj,
    const float* __restrict__ bproj, float* __restrict__ out)
{
    const int bid = blockIdx.x;                       // 1568 = 8 * 196
    const int swz = (bid & 7) * 196 + (bid >> 3);
    const int nt = swz & 3;
    const int mt = swz >> 2;
    const u16* Asrc = attn_out;
    const u16* Bsrc = WtProj + (size_t)(nt * 128) * 512;
    GEMM_PROLOG()

#pragma unroll
    for (int j = 0; j < 4; ++j) {
        const int col = nt * 128 + wc * 64 + j * 16 + rowl;   // 0..511
        const float bias_ = bproj[col];
#pragma unroll
        for (int i = 0; i < 4; ++i) {
#pragma unroll
            for (int r = 0; r < 4; ++r) {
                const int row = mt * 128 + wr * 64 + i * 16 + kg * 4 + r;
                const int win = row / 49;
                const int nw = row - win * 49;
                const int b = win >> 6, wi = win & 63;
                const int wh = wi >> 3, ww = wi & 7;
                const int ih = nw / 7, iw = nw - ih * 7;
                int h = wh * 7 + ih + 3; if (h >= 56) h -= 56;  // roll(+3)
                int w = ww * 7 + iw + 3; if (w >= 56) w -= 56;
                out[((size_t)b * 3136 + (size_t)h * 56 + w) * 512 + col] =
                    acc[i][j][r] + bias_;
            }
        }
    }
}

// ---------------------------------------------------------------------------
// Kernel 4: MFMA windowed cross-attention.  One block per (window, head),
// 4 waves; wave w owns S row-tile w (16 rows).
//   S   = Q K^T : 4 MFMAs/wave (K=32 = full head dim), frags direct-global.
//   softmax in-register (16-lane shuffle groups), 1/sum deferred to epilogue.
//   P (bf16, unnormalized) -> LDS (XOR-chunk swizzle, wave-local rows).
//   O   = P V   : 4 MFMAs/wave, V^T staged in LDS (XOR-chunk swizzle).
// Padded rows/cols (49..63) read the next plane's real finite data; the bias
// table's -3e38 masks padded cols exactly (exp -> 0); padded Q rows only
// affect unused O rows.
// ---------------------------------------------------------------------------
__global__ __launch_bounds__(256) void attn_kernel(
    const u16* __restrict__ qb, const u16* __restrict__ kb,
    const u16* __restrict__ vb, const float* __restrict__ bias,
    u16* __restrict__ attn_out)
{
    __shared__ __align__(16) u16 VT[32 * 64];   // [d][chunk^(d&7)*8 + j&7]
    __shared__ __align__(16) u16 P[64 * 64];    // [row][chunk^(row&7)*8 + j&7]
    const int tid = threadIdx.x;
    const int wh_id = blockIdx.x;               // win*16 + head
    const int win = wh_id >> 4, head = wh_id & 15;
    const int lane = tid & 63, wvi = tid >> 6;  // wvi = row-tile
    const int rowl = lane & 15, kg = lane >> 4;
    const size_t base = (size_t)win * 49 * 512 + head * 32;

    // ---- stage V^T (thread t: row j = t>>2, d0 = (t&3)*8)
    {
        const int j = tid >> 2, d0 = (tid & 3) * 8;
        const bf16x8 v8 = *(const bf16x8*)(vb + base + (size_t)j * 512 + d0);
        const int cj = j >> 3, je = j & 7;
#pragma unroll
        for (int m = 0; m < 8; ++m) {
            const int d = d0 + m;
            VT[d * 64 + ((cj ^ (d & 7)) * 8) + je] = (u16)v8[m];
        }
    }

    // ---- S = Q K^T (direct-global fragments)
    const bf16x8 aq = *(const bf16x8*)(qb + base + (size_t)(wvi * 16 + rowl) * 512 + kg * 8);
    f32x4 accS[4];
#pragma unroll
    for (int j = 0; j < 4; ++j) {
        const bf16x8 bk = *(const bf16x8*)(kb + base + (size_t)(j * 16 + rowl) * 512 + kg * 8);
        accS[j] = __builtin_amdgcn_mfma_f32_16x16x32_bf16(
            aq, bk, (f32x4){0.f, 0.f, 0.f, 0.f}, 0, 0, 0);
    }

    // ---- + bias (rpb + window mask + pad mask)
    const int wi = win & 63;
    const int mid = (((wi >> 3) == 7) ? 2 : 0) + (((wi & 7) == 7) ? 1 : 0);
    const float* bptr = bias + ((size_t)(mid * 16 + head) << 12);
#pragma unroll
    for (int j = 0; j < 4; ++j)
#pragma unroll
        for (int r = 0; r < 4; ++r)
            accS[j][r] += bptr[(wvi * 16 + kg * 4 + r) * 64 + j * 16 + rowl];

    // ---- softmax rows (row i = wvi*16+kg*4+r lives in one 16-lane group)
    float rinv[4];
#pragma unroll
    for (int r = 0; r < 4; ++r) {
        float m = fmaxf(fmaxf(accS[0][r], accS[1][r]), fmaxf(accS[2][r], accS[3][r]));
#pragma unroll
        for (int o = 1; o <= 8; o <<= 1) m = fmaxf(m, __shfl_xor(m, o));
        float s = 0.f;
#pragma unroll
        for (int j = 0; j < 4; ++j) {
            accS[j][r] = __expf(accS[j][r] - m);
            s += accS[j][r];
        }
#pragma unroll
        for (int o = 1; o <= 8; o <<= 1) s += __shfl_xor(s, o);
        rinv[r] = __frcp_rn(s);
    }

    // ---- P -> LDS (bf16, unnormalized; wave-local rows)
#pragma unroll
    for (int j = 0; j < 4; ++j) {
        const int c = j * 2 + (rowl >> 3);
#pragma unroll
        for (int r = 0; r < 4; ++r) {
            const int row = wvi * 16 + kg * 4 + r;
            P[row * 64 + ((c ^ (row & 7)) * 8) + (rowl & 7)] = f2bf(accS[j][r]);
        }
    }

    __syncthreads();   // VT visible to all waves (P rows are wave-local)

    // ---- O = P V
    f32x4 accO[2];
#pragma unroll
    for (int dt = 0; dt < 2; ++dt) {
        accO[dt] = (f32x4){0.f, 0.f, 0.f, 0.f};
#pragma unroll
        for (int kb_ = 0; kb_ < 2; ++kb_) {
            const int prow = wvi * 16 + rowl;
            const int ca = kb_ * 4 + kg;
            const bf16x8 ap = *(const bf16x8*)(P + prow * 64 + ((ca ^ (prow & 7)) * 8));
            const int vd = dt * 16 + rowl;
            const bf16x8 bv = *(const bf16x8*)(VT + vd * 64 + ((ca ^ (vd & 7)) * 8));
            accO[dt] = __builtin_amdgcn_mfma_f32_16x16x32_bf16(ap, bv, accO[dt], 0, 0, 0);
        }
    }

    // ---- scale by 1/sum, store rows < 49
#pragma unroll
    for (int dt = 0; dt < 2; ++dt) {
#pragma unroll
        for (int r = 0; r < 4; ++r) {
            const int i = wvi * 16 + kg * 4 + r;
            if (i < 49)
                attn_out[base + (size_t)i * 512 + dt * 16 + rowl] =
                    f2bf(accO[dt][r] * rinv[r]);
        }
    }
}

// ---------------------------------------------------------------------------
extern "C" void kernel_launch(void* const* d_in, const int* in_sizes, int n_in,
                              void* d_out, int out_size, void* d_ws, size_t ws_size,
                              hipStream_t stream) {
    (void)in_sizes; (void)n_in; (void)out_size; (void)ws_size;
    const float* rescaled = (const float*)d_in[0];
    const float* rescaler = (const float*)d_in[1];
    const float* gamma_a  = (const float*)d_in[2];
    const float* beta_a   = (const float*)d_in[3];
    const float* gamma_b  = (const float*)d_in[4];
    const float* beta_b   = (const float*)d_in[5];
    const float* Wqkv_a   = (const float*)d_in[6];
    const float* bqkv_a   = (const float*)d_in[7];
    const float* Wqkv_b   = (const float*)d_in[8];
    const float* bqkv_b   = (const float*)d_in[9];
    const float* rpb      = (const float*)d_in[10];
    const float* Wproj    = (const float*)d_in[11];
    const float* bproj    = (const float*)d_in[12];
    float* out = (float*)d_out;

    char* ws = (char*)d_ws;
    const size_t SZ = (size_t)MTOT * 512 * 2;     // 51,380,224 B per bf16 plane
    u16* xw = (u16*)ws;                           // reused as attn_out
    u16* yw = (u16*)(ws + SZ);
    u16* qb = (u16*)(ws + 2 * SZ);
    u16* kb = (u16*)(ws + 3 * SZ);                // attn K overrun -> vb (real data)
    u16* vb = (u16*)(ws + 4 * SZ);                // attn V overrun -> Wt (real data)
    u16* Wt = (u16*)(ws + 5 * SZ);                // 2 MB
    float* bias = (float*)(ws + 5 * SZ + 2097152);// 1 MB
    u16* attn_out = xw;

    wconv_kernel<<<4096, 256, 0, stream>>>(Wqkv_a, Wqkv_b, Wproj, Wt);
    build_bias_kernel<<<64, 256, 0, stream>>>(rpb, bias);
    ln_window_kernel<<<MTOT / 4, 256, 0, stream>>>(
        rescaled, rescaler, gamma_a, beta_a, gamma_b, beta_b, xw, yw);
    gemm_qkv_kernel<<<4704, 256, 0, stream>>>(
        xw, yw, Wt, bqkv_a, bqkv_b, qb, kb, vb);
    attn_kernel<<<16384, 256, 0, stream>>>(qb, kb, vb, bias, attn_out);
    gemm_proj_kernel<<<1568, 256, 0, stream>>>(
        attn_out, Wt + (size_t)1536 * 512, bproj, out);
}

// Round 5
// 521.109 us; speedup vs baseline: 1.5126x; 1.1093x over previous
//
#include <hip/hip_runtime.h>
#include <hip/hip_bf16.h>

// ---------------------------------------------------------------------------
// Swin cross-attention block, MI355X (gfx950).
// Config: B=16, H=W=56, C=512, WS=7, SHIFT=3, NH=16, HD=32, N=49, NW=64.
// M = B*NW*N = 50176 rows. Only q_b, k_a, v_a are consumed by the reference.
//
// Workspace (~260 MB):
//   xw : 50176x512 bf16  [reused as attn_out]
//   yw : 50176x512 bf16
//   qb/kb/vb : 50176x512 bf16 (row=win*49+n, col=head*32+d)
//   Wt : 2048x512 bf16 (transposed weight panels)
//   bias : [4 masks][16 heads][64][64] fp32 (rpb + window mask + pad mask)
// ---------------------------------------------------------------------------

typedef short bf16x8 __attribute__((ext_vector_type(8)));
typedef float f32x4 __attribute__((ext_vector_type(4)));
typedef unsigned short u16;

#define MTOT 50176
#define SCALE_ 0.17677669529663687f

__device__ __forceinline__ u16 f2bf(float f) {
    __hip_bfloat16 h = __float2bfloat16(f);
    return *reinterpret_cast<u16*>(&h);
}
__device__ __forceinline__ float bf2f(u16 u) {
    union { unsigned int i; float f; } t; t.i = ((unsigned int)u) << 16; return t.f;
}

#define ASYNC_COPY16(g, l)                                                      \
    __builtin_amdgcn_global_load_lds((__attribute__((address_space(1))) void*)(g), \
                                     (__attribute__((address_space(3))) void*)(l), 16, 0, 0)

// ---------------------------------------------------------------------------
// Kernel 1: weight transpose + fp32->bf16.  Wt[r][k], r = output col.
// ---------------------------------------------------------------------------
__global__ __launch_bounds__(256) void wconv_kernel(
    const float* __restrict__ Wqkv_a, const float* __restrict__ Wqkv_b,
    const float* __restrict__ Wproj, u16* __restrict__ Wt)
{
    const int idx = blockIdx.x * 256 + threadIdx.x;   // 2048*512
    const int r = idx >> 9;
    const int k = idx & 511;
    float val;
    if (r < 512)       val = Wqkv_b[k * 1536 + r];
    else if (r < 1536) val = Wqkv_a[k * 1536 + r];
    else               val = Wproj[k * 512 + (r - 1536)];
    Wt[idx] = f2bf(val);
}

// ---------------------------------------------------------------------------
// Kernel 1b: per-(mask,head) bias table: rpb + shifted-window mask, padded
// cols/rows (>=49) = -3e38.  bias[(mid*16+head)*4096 + i*64 + j].
// ---------------------------------------------------------------------------
__global__ __launch_bounds__(256) void build_bias_kernel(
    const float* __restrict__ rpb, float* __restrict__ bias)
{
    const int blk = blockIdx.x;           // 64 = mid*16 + head
    const int mid = blk >> 4, head = blk & 15;
    const int whq = (mid >> 1) & 1, wwq = mid & 1;
    for (int t = threadIdx.x; t < 4096; t += 256) {
        const int i = t >> 6, j = t & 63;
        float v;
        if (i < 49 && j < 49) {
            const int ih = i / 7, iw = i - ih * 7;
            const int jh = j / 7, jw = j - jh * 7;
            v = rpb[((ih - jh + 6) * 13 + (iw - jw + 6)) * 16 + head];
            const int li = (whq ? (ih < 4 ? 1 : 2) : 0) * 3 + (wwq ? (iw < 4 ? 1 : 2) : 0);
            const int lj = (whq ? (jh < 4 ? 1 : 2) : 0) * 3 + (wwq ? (jw < 4 ? 1 : 2) : 0);
            if (li != lj) v -= 100.0f;
        } else {
            v = -3.0e38f;
        }
        bias[(size_t)blk * 4096 + t] = v;
    }
}

// ---------------------------------------------------------------------------
// Kernel 2: LayerNorm + roll(-3,-3) + window partition, both streams -> bf16.
// ---------------------------------------------------------------------------
__device__ __forceinline__ void ln_one(
    const float* __restrict__ src, const float* __restrict__ g,
    const float* __restrict__ bt, u16* __restrict__ dst, int lane)
{
    const float4 v0 = *(const float4*)(src + lane * 8);
    const float4 v1 = *(const float4*)(src + lane * 8 + 4);
    float s = v0.x + v0.y + v0.z + v0.w + v1.x + v1.y + v1.z + v1.w;
    float q = v0.x*v0.x + v0.y*v0.y + v0.z*v0.z + v0.w*v0.w
            + v1.x*v1.x + v1.y*v1.y + v1.z*v1.z + v1.w*v1.w;
#pragma unroll
    for (int o = 32; o >= 1; o >>= 1) { s += __shfl_xor(s, o); q += __shfl_xor(q, o); }
    const float mean = s * (1.0f / 512.0f);
    const float rstd = rsqrtf(q * (1.0f / 512.0f) - mean * mean + 1e-5f);
    const float4 g0 = *(const float4*)(g + lane * 8);
    const float4 g1 = *(const float4*)(g + lane * 8 + 4);
    const float4 b0 = *(const float4*)(bt + lane * 8);
    const float4 b1 = *(const float4*)(bt + lane * 8 + 4);
    u16 o8[8];
    o8[0] = f2bf((v0.x - mean) * rstd * g0.x + b0.x);
    o8[1] = f2bf((v0.y - mean) * rstd * g0.y + b0.y);
    o8[2] = f2bf((v0.z - mean) * rstd * g0.z + b0.z);
    o8[3] = f2bf((v0.w - mean) * rstd * g0.w + b0.w);
    o8[4] = f2bf((v1.x - mean) * rstd * g1.x + b1.x);
    o8[5] = f2bf((v1.y - mean) * rstd * g1.y + b1.y);
    o8[6] = f2bf((v1.z - mean) * rstd * g1.z + b1.z);
    o8[7] = f2bf((v1.w - mean) * rstd * g1.w + b1.w);
    int4 pk;
    pk.x = (int)(((unsigned)o8[1] << 16) | o8[0]);
    pk.y = (int)(((unsigned)o8[3] << 16) | o8[2]);
    pk.z = (int)(((unsigned)o8[5] << 16) | o8[4]);
    pk.w = (int)(((unsigned)o8[7] << 16) | o8[6]);
    *(int4*)(dst + lane * 8) = pk;
}

__global__ __launch_bounds__(256) void ln_window_kernel(
    const float* __restrict__ xa, const float* __restrict__ xb,
    const float* __restrict__ ga, const float* __restrict__ bea,
    const float* __restrict__ gb, const float* __restrict__ beb,
    u16* __restrict__ xw, u16* __restrict__ yw)
{
    const int wave = threadIdx.x >> 6, lane = threadIdx.x & 63;
    const int row = blockIdx.x * 4 + wave;             // < 50176
    const int win = row / 49, n = row - win * 49;
    const int b = win >> 6, wi = win & 63;
    const int wh = wi >> 3, ww = wi & 7;
    const int ih = n / 7, iw = n - ih * 7;
    int h = wh * 7 + ih + 3; if (h >= 56) h -= 56;     // roll(-3)
    int w = ww * 7 + iw + 3; if (w >= 56) w -= 56;
    const size_t src = ((size_t)b * 3136 + (size_t)h * 56 + w) * 512;
    const size_t dst = (size_t)row * 512;
    ln_one(xa + src, ga, bea, xw + dst, lane);
    ln_one(xb + src, gb, beb, yw + dst, lane);
}

// ---------------------------------------------------------------------------
// 8-wave GEMM mainloop: 128(M)x256(N) tile, BK=64, 16x16x32 bf16 MFMA.
// Wave grid 2(M)x4(N); per-wave 64x64 output (acc[4][4]).
// LDS: As 128x64 (16 KB) + Bs 256x64 (32 KB) = 48 KB.
// XOR swizzle (G4): 16B chunk c of row r holds logical chunk c^(r&7).
// Applied via pre-swizzled GLOBAL source (LDS dest stays linear for
// global_load_lds) + XOR on the ds_read side -> conflict-free frag reads.
// ---------------------------------------------------------------------------
#define GEMM8_MAIN()                                                            \
    __shared__ __align__(16) u16 As[128 * 64];                                  \
    __shared__ __align__(16) u16 Bs[256 * 64];                                  \
    const int tid = threadIdx.x;                                                \
    const int lane = tid & 63;                                                  \
    const int wv = tid >> 6;                                                    \
    const int wm = wv >> 2, wn = wv & 3;                                        \
    const int rowl = lane & 15, kg = lane >> 4;                                 \
    const int sw = rowl & 7;                                                    \
    f32x4 acc[4][4];                                                            \
    for (int i = 0; i < 4; ++i)                                                 \
        for (int j = 0; j < 4; ++j)                                             \
            acc[i][j] = (f32x4){0.f, 0.f, 0.f, 0.f};                            \
    const int srow = tid >> 3;                                                  \
    const int clog = (tid & 7) ^ (srow & 7);                                    \
    const u16* Ab = Asrc + (size_t)(mt * 128 + srow) * 512 + clog * 8;          \
    const u16* Bb = Bsrc + (size_t)srow * 512 + clog * 8;                       \
    char* AsD = (char*)As + tid * 16;                                           \
    char* BsD = (char*)Bs + tid * 16;                                           \
    for (int kt = 0; kt < 8; ++kt) {                                            \
        const int k0 = kt * 64;                                                 \
        _Pragma("unroll")                                                       \
        for (int r = 0; r < 2; ++r)                                             \
            ASYNC_COPY16(Ab + (size_t)r * 64 * 512 + k0, AsD + r * 8192);       \
        _Pragma("unroll")                                                       \
        for (int r = 0; r < 4; ++r)                                             \
            ASYNC_COPY16(Bb + (size_t)r * 64 * 512 + k0, BsD + r * 8192);       \
        asm volatile("s_waitcnt vmcnt(0)" ::: "memory");                        \
        __syncthreads();                                                        \
        _Pragma("unroll")                                                       \
        for (int kk = 0; kk < 2; ++kk) {                                        \
            const int kch = kg + kk * 4;                                        \
            const int sco = (kch ^ sw) * 8;                                     \
            bf16x8 af[4], bfr[4];                                               \
            _Pragma("unroll")                                                   \
            for (int i = 0; i < 4; ++i)                                         \
                af[i] = *(const bf16x8*)(As + (wm * 64 + i * 16 + rowl) * 64 + sco); \
            _Pragma("unroll")                                                   \
            for (int j = 0; j < 4; ++j)                                         \
                bfr[j] = *(const bf16x8*)(Bs + (wn * 64 + j * 16 + rowl) * 64 + sco); \
            _Pragma("unroll")                                                   \
            for (int i = 0; i < 4; ++i) {                                       \
                _Pragma("unroll")                                               \
                for (int j = 0; j < 4; ++j)                                     \
                    acc[i][j] = __builtin_amdgcn_mfma_f32_16x16x32_bf16(        \
                        af[i], bfr[j], acc[i][j], 0, 0, 0);                     \
            }                                                                   \
        }                                                                       \
        __syncthreads();                                                        \
    }

// Kernel 3: q/k/v projection.  Grid 2352 = 392 mt x 6 nt (nt-fastest,
// bijective XCD swizzle).  nt 0-1: q (A=yw); 2-3: k (A=xw); 4-5: v (A=xw).
// Each block lies entirely in one output plane (BN=256 < 512).
__global__ __launch_bounds__(512) void gemm_qkv_kernel(
    const u16* __restrict__ xw, const u16* __restrict__ yw,
    const u16* __restrict__ Wt,
    const float* __restrict__ bqkv_a, const float* __restrict__ bqkv_b,
    u16* __restrict__ qb, u16* __restrict__ kb, u16* __restrict__ vb)
{
    const int bid = blockIdx.x;                       // 2352 = 8 * 294
    const int swz = (bid & 7) * 294 + (bid >> 3);
    const int nt = swz % 6;
    const int mt = swz / 6;
    const u16* Asrc = (nt < 2) ? yw : xw;
    const u16* Bsrc = Wt + (size_t)(nt * 256) * 512;
    GEMM8_MAIN()

    u16* dst; const float* bvec; bool isq = false;
    if (nt < 2)      { dst = qb; bvec = bqkv_b; isq = true; }
    else if (nt < 4) { dst = kb; bvec = bqkv_a; }
    else             { dst = vb; bvec = bqkv_a; }
#pragma unroll
    for (int j = 0; j < 4; ++j) {
        const int col = nt * 256 + wn * 64 + j * 16 + rowl;   // 0..1535
        const float bias_ = bvec[col];
        const int pcol = col & 511;
#pragma unroll
        for (int i = 0; i < 4; ++i) {
#pragma unroll
            for (int rr = 0; rr < 4; ++rr) {
                const int row = mt * 128 + wm * 64 + i * 16 + kg * 4 + rr;
                float val = acc[i][j][rr] + bias_;
                if (isq) val *= SCALE_;
                dst[(size_t)row * 512 + pcol] = f2bf(val);
            }
        }
    }
}

// Kernel 5: output projection + bias + window_reverse + roll(+3,+3), fp32 out.
// Grid 784 = 392 mt x 2 nt.
__global__ __launch_bounds__(512) void gemm_proj_kernel(
    const u16* __restrict__ attn_out, const u16* __restrict__ WtProj,
    const float* __restrict__ bproj, float* __restrict__ out)
{
    const int bid = blockIdx.x;                       // 784 = 8 * 98
    const int swz = (bid & 7) * 98 + (bid >> 3);
    const int nt = swz & 1;
    const int mt = swz >> 1;
    const u16* Asrc = attn_out;
    const u16* Bsrc = WtProj + (size_t)(nt * 256) * 512;
    GEMM8_MAIN()

#pragma unroll
    for (int j = 0; j < 4; ++j) {
        const int col = nt * 256 + wn * 64 + j * 16 + rowl;   // 0..511
        const float bias_ = bproj[col];
#pragma unroll
        for (int i = 0; i < 4; ++i) {
#pragma unroll
            for (int rr = 0; rr < 4; ++rr) {
                const int row = mt * 128 + wm * 64 + i * 16 + kg * 4 + rr;
                const int win = row / 49;
                const int nw = row - win * 49;
                const int b = win >> 6, wi = win & 63;
                const int wh = wi >> 3, ww = wi & 7;
                const int ih = nw / 7, iw = nw - ih * 7;
                int h = wh * 7 + ih + 3; if (h >= 56) h -= 56;  // roll(+3)
                int w = ww * 7 + iw + 3; if (w >= 56) w -= 56;
                out[((size_t)b * 3136 + (size_t)h * 56 + w) * 512 + col] =
                    acc[i][j][rr] + bias_;
            }
        }
    }
}

// ---------------------------------------------------------------------------
// Kernel 4: MFMA windowed cross-attention.  One block per (window, head),
// 4 waves; wave w owns S row-tile w (16 rows).
// ---------------------------------------------------------------------------
__global__ __launch_bounds__(256) void attn_kernel(
    const u16* __restrict__ qb, const u16* __restrict__ kb,
    const u16* __restrict__ vb, const float* __restrict__ bias,
    u16* __restrict__ attn_out)
{
    __shared__ __align__(16) u16 VT[32 * 64];   // [d][chunk^(d&7)*8 + j&7]
    __shared__ __align__(16) u16 P[64 * 64];    // [row][chunk^(row&7)*8 + j&7]
    const int tid = threadIdx.x;
    const int wh_id = blockIdx.x;               // win*16 + head
    const int win = wh_id >> 4, head = wh_id & 15;
    const int lane = tid & 63, wvi = tid >> 6;
    const int rowl = lane & 15, kg = lane >> 4;
    const size_t base = (size_t)win * 49 * 512 + head * 32;

    // ---- stage V^T
    {
        const int j = tid >> 2, d0 = (tid & 3) * 8;
        const bf16x8 v8 = *(const bf16x8*)(vb + base + (size_t)j * 512 + d0);
        const int cj = j >> 3, je = j & 7;
#pragma unroll
        for (int m = 0; m < 8; ++m) {
            const int d = d0 + m;
            VT[d * 64 + ((cj ^ (d & 7)) * 8) + je] = (u16)v8[m];
        }
    }

    // ---- S = Q K^T (direct-global fragments)
    const bf16x8 aq = *(const bf16x8*)(qb + base + (size_t)(wvi * 16 + rowl) * 512 + kg * 8);
    f32x4 accS[4];
#pragma unroll
    for (int j = 0; j < 4; ++j) {
        const bf16x8 bk = *(const bf16x8*)(kb + base + (size_t)(j * 16 + rowl) * 512 + kg * 8);
        accS[j] = __builtin_amdgcn_mfma_f32_16x16x32_bf16(
            aq, bk, (f32x4){0.f, 0.f, 0.f, 0.f}, 0, 0, 0);
    }

    // ---- + bias (rpb + window mask + pad mask)
    const int wi = win & 63;
    const int mid = (((wi >> 3) == 7) ? 2 : 0) + (((wi & 7) == 7) ? 1 : 0);
    const float* bptr = bias + ((size_t)(mid * 16 + head) << 12);
#pragma unroll
    for (int j = 0; j < 4; ++j)
#pragma unroll
        for (int r = 0; r < 4; ++r)
            accS[j][r] += bptr[(wvi * 16 + kg * 4 + r) * 64 + j * 16 + rowl];

    // ---- softmax rows (row lives in one 16-lane group)
    float rinv[4];
#pragma unroll
    for (int r = 0; r < 4; ++r) {
        float m = fmaxf(fmaxf(accS[0][r], accS[1][r]), fmaxf(accS[2][r], accS[3][r]));
#pragma unroll
        for (int o = 1; o <= 8; o <<= 1) m = fmaxf(m, __shfl_xor(m, o));
        float s = 0.f;
#pragma unroll
        for (int j = 0; j < 4; ++j) {
            accS[j][r] = __expf(accS[j][r] - m);
            s += accS[j][r];
        }
#pragma unroll
        for (int o = 1; o <= 8; o <<= 1) s += __shfl_xor(s, o);
        rinv[r] = __frcp_rn(s);
    }

    // ---- P -> LDS (bf16, unnormalized; wave-local rows)
#pragma unroll
    for (int j = 0; j < 4; ++j) {
        const int c = j * 2 + (rowl >> 3);
#pragma unroll
        for (int r = 0; r < 4; ++r) {
            const int row = wvi * 16 + kg * 4 + r;
            P[row * 64 + ((c ^ (row & 7)) * 8) + (rowl & 7)] = f2bf(accS[j][r]);
        }
    }

    __syncthreads();

    // ---- O = P V
    f32x4 accO[2];
#pragma unroll
    for (int dt = 0; dt < 2; ++dt) {
        accO[dt] = (f32x4){0.f, 0.f, 0.f, 0.f};
#pragma unroll
        for (int kb_ = 0; kb_ < 2; ++kb_) {
            const int prow = wvi * 16 + rowl;
            const int ca = kb_ * 4 + kg;
            const bf16x8 ap = *(const bf16x8*)(P + prow * 64 + ((ca ^ (prow & 7)) * 8));
            const int vd = dt * 16 + rowl;
            const bf16x8 bv = *(const bf16x8*)(VT + vd * 64 + ((ca ^ (vd & 7)) * 8));
            accO[dt] = __builtin_amdgcn_mfma_f32_16x16x32_bf16(ap, bv, accO[dt], 0, 0, 0);
        }
    }

    // ---- scale by 1/sum, store rows < 49
#pragma unroll
    for (int dt = 0; dt < 2; ++dt) {
#pragma unroll
        for (int r = 0; r < 4; ++r) {
            const int i = wvi * 16 + kg * 4 + r;
            if (i < 49)
                attn_out[base + (size_t)i * 512 + dt * 16 + rowl] =
                    f2bf(accO[dt][r] * rinv[r]);
        }
    }
}

// ---------------------------------------------------------------------------
extern "C" void kernel_launch(void* const* d_in, const int* in_sizes, int n_in,
                              void* d_out, int out_size, void* d_ws, size_t ws_size,
                              hipStream_t stream) {
    (void)in_sizes; (void)n_in; (void)out_size; (void)ws_size;
    const float* rescaled = (const float*)d_in[0];
    const float* rescaler = (const float*)d_in[1];
    const float* gamma_a  = (const float*)d_in[2];
    const float* beta_a   = (const float*)d_in[3];
    const float* gamma_b  = (const float*)d_in[4];
    const float* beta_b   = (const float*)d_in[5];
    const float* Wqkv_a   = (const float*)d_in[6];
    const float* bqkv_a   = (const float*)d_in[7];
    const float* Wqkv_b   = (const float*)d_in[8];
    const float* bqkv_b   = (const float*)d_in[9];
    const float* rpb      = (const float*)d_in[10];
    const float* Wproj    = (const float*)d_in[11];
    const float* bproj    = (const float*)d_in[12];
    float* out = (float*)d_out;

    char* ws = (char*)d_ws;
    const size_t SZ = (size_t)MTOT * 512 * 2;     // 51,380,224 B per bf16 plane
    u16* xw = (u16*)ws;                           // reused as attn_out
    u16* yw = (u16*)(ws + SZ);
    u16* qb = (u16*)(ws + 2 * SZ);
    u16* kb = (u16*)(ws + 3 * SZ);
    u16* vb = (u16*)(ws + 4 * SZ);
    u16* Wt = (u16*)(ws + 5 * SZ);                // 2 MB
    float* bias = (float*)(ws + 5 * SZ + 2097152);// 1 MB
    u16* attn_out = xw;

    wconv_kernel<<<4096, 256, 0, stream>>>(Wqkv_a, Wqkv_b, Wproj, Wt);
    build_bias_kernel<<<64, 256, 0, stream>>>(rpb, bias);
    ln_window_kernel<<<MTOT / 4, 256, 0, stream>>>(
        rescaled, rescaler, gamma_a, beta_a, gamma_b, beta_b, xw, yw);
    gemm_qkv_kernel<<<2352, 512, 0, stream>>>(
        xw, yw, Wt, bqkv_a, bqkv_b, qb, kb, vb);
    attn_kernel<<<16384, 256, 0, stream>>>(qb, kb, vb, bias, attn_out);
    gemm_proj_kernel<<<784, 512, 0, stream>>>(
        attn_out, Wt + (size_t)1536 * 512, bproj, out);
}